// Round 2
// baseline (1509.876 us; speedup 1.0000x reference)
//
#include <hip/hip_runtime.h>
#include <math.h>

#define HWSZ 6400
#define WIMG 80
#define HIMG 80
#define BEPS 1e-5f

__device__ __forceinline__ float bn_silu(float a, float inv, float bet) {
    float t = fmaf(a, inv, bet);
    return t / (1.f + __expf(-t));
}

// ---------------- Kernel A: cv1 (1x1, 256->128) + bn1 + silu -> y1 (chan-major) + y1t (pixel-major) ----
// grid: 8 * 100 blocks, 256 threads. Block tile: O=128, P=64. acc[32]/thread.
__global__ __launch_bounds__(256) void k_cv1(
    const float* __restrict__ x, const float* __restrict__ w,
    const float* __restrict__ g, const float* __restrict__ bb,
    const float* __restrict__ mm, const float* __restrict__ vv,
    float* __restrict__ y1, float* __restrict__ y1t)
{
    __shared__ float xt[64][64];
    __shared__ float tr[64][68];   // transpose buffer, stride 68 (16B-aligned rows)
    int blk = blockIdx.x;
    int b = blk / 100, pt = blk % 100;
    int p0 = pt * 64;
    int tid = threadIdx.x;
    int p = tid & 63;
    int obase = __builtin_amdgcn_readfirstlane((tid >> 6) * 32);
    float acc[32];
#pragma unroll
    for (int i = 0; i < 32; ++i) acc[i] = 0.f;
    const float* xb = x + (size_t)b * 256 * HWSZ + p0;
    for (int cc = 0; cc < 256; cc += 64) {
        __syncthreads();
        for (int i = tid; i < 64 * 64; i += 256) {
            int c = i >> 6, pp = i & 63;
            xt[c][pp] = xb[(size_t)(cc + c) * HWSZ + pp];
        }
        __syncthreads();
#pragma unroll 4
        for (int c = 0; c < 64; ++c) {
            float xv = xt[c][p];
            const float* wrow = w + (size_t)obase * 256 + (cc + c);
#pragma unroll
            for (int i = 0; i < 32; ++i)
                acc[i] = fmaf(xv, wrow[(size_t)i * 256], acc[i]);
        }
    }
    float vout[32];
#pragma unroll
    for (int i = 0; i < 32; ++i) {
        int o = obase + i;
        float inv = g[o] * rsqrtf(vv[o] + BEPS);
        float bet = bb[o] - mm[o] * inv;
        vout[i] = bn_silu(acc[i], inv, bet);
    }
    // channel-major write (k_off consumes this, coalesced)
    float* yb = y1 + (size_t)b * 128 * HWSZ + p0 + p;
#pragma unroll
    for (int i = 0; i < 32; ++i)
        yb[(size_t)(obase + i) * HWSZ] = vout[i];

    // pixel-major write via LDS transpose, two 64-channel halves
    float* ytb = y1t + ((size_t)b * HWSZ + p0) * 128;
#pragma unroll
    for (int half = 0; half < 2; ++half) {
        __syncthreads();
        if ((obase >> 6) == half) {
            int ob = obase & 63;
#pragma unroll
            for (int i4 = 0; i4 < 8; ++i4) {
                float4 v = { vout[i4 * 4], vout[i4 * 4 + 1], vout[i4 * 4 + 2], vout[i4 * 4 + 3] };
                *(float4*)&tr[p][ob + i4 * 4] = v;
            }
        }
        __syncthreads();
        int c4 = (tid & 15) * 4;
        int r0 = tid >> 4;
#pragma unroll
        for (int r = 0; r < 4; ++r) {
            int row = r0 + r * 16;
            float4 v = *(const float4*)&tr[row][c4];
            *(float4*)&ytb[(size_t)row * 128 + half * 64 + c4] = v;
        }
    }
}

// ---------------- Kernel B: 3x3 conv (128->27) + bias; sigmoid on mask channels ----
__global__ __launch_bounds__(256) void k_off(
    const float* __restrict__ y1, const float* __restrict__ w,
    const float* __restrict__ bias, float* __restrict__ raw)
{
    int blk = blockIdx.x;
    int b = blk / 25, pt = blk % 25;
    int p = pt * 256 + threadIdx.x;
    int h = p / WIMG, wx = p % WIMG;
    int idx[9];
#pragma unroll
    for (int n = 0; n < 9; ++n) {
        int yy = h - 1 + n / 3;
        int xx = wx - 1 + n % 3;
        bool valid = ((unsigned)yy < HIMG) && ((unsigned)xx < WIMG);
        idx[n] = valid ? (yy * WIMG + xx) : -1;
    }
    float acc[27];
#pragma unroll
    for (int o = 0; o < 27; ++o) acc[o] = 0.f;
    const float* yb = y1 + (size_t)b * 128 * HWSZ;
    for (int c = 0; c < 128; ++c) {
        const float* yc = yb + (size_t)c * HWSZ;
        float tv[9];
#pragma unroll
        for (int n = 0; n < 9; ++n) tv[n] = (idx[n] >= 0) ? yc[idx[n]] : 0.f;
        const float* wc = w + (size_t)c * 9;
#pragma unroll
        for (int o = 0; o < 27; ++o) {
#pragma unroll
            for (int n = 0; n < 9; ++n)
                acc[o] = fmaf(tv[n], wc[(size_t)o * 1152 + n], acc[o]);
        }
    }
    float* rb = raw + (size_t)b * 27 * HWSZ + p;
#pragma unroll
    for (int o = 0; o < 27; ++o) {
        float t = acc[o] + bias[o];
        if (o >= 18) t = 1.f / (1.f + __expf(-t));  // sigmoid for mask channels
        rb[(size_t)o * HWSZ] = t;
    }
}

// ---------------- Kernel C: DCNv2 + bn2 + silu -> z ----------------
// grid: 8 * 100 blocks, 256 threads. Tile: O=128, P=64, K chunks of 16 ch * 9 taps.
// Gathers read pixel-major y1t as float4 (4 channels per load).
__global__ __launch_bounds__(256) void k_dcn(
    const float* __restrict__ y1t, const float* __restrict__ raw,
    const float* __restrict__ w, const float* __restrict__ bias,
    const float* __restrict__ g, const float* __restrict__ bb,
    const float* __restrict__ mm, const float* __restrict__ vv,
    float* __restrict__ z)
{
    __shared__ float sval[144][64];
    __shared__ float swgt[4][9][64];
    __shared__ unsigned short sidx[4][9][64];
    int blk = blockIdx.x;
    int b = blk / 100, pt = blk % 100;
    int p0 = pt * 64;
    int tid = threadIdx.x;

    // Stage 1: per (tap, pixel): 4 corner indices + weights (validity * bilinear * mask)
    for (int i = tid; i < 9 * 64; i += 256) {
        int n = i / 64, pp = i % 64;
        int p = p0 + pp;
        int h = p / WIMG, wx = p % WIMG;
        const float* rb = raw + (size_t)b * 27 * HWSZ + p;
        float dy = rb[(size_t)(2 * n) * HWSZ];
        float dx = rb[(size_t)(2 * n + 1) * HWSZ];
        float mk = rb[(size_t)(18 + n) * HWSZ];   // already sigmoided
        float py = (float)(h - 1 + n / 3) + dy;
        float px = (float)(wx - 1 + n % 3) + dx;
        float y0f = floorf(py), x0f = floorf(px);
        float fy = py - y0f, fx = px - x0f;
        int y0 = (int)y0f, x0 = (int)x0f;
#pragma unroll
        for (int k = 0; k < 4; ++k) {
            int yy = y0 + (k >> 1);
            int xx = x0 + (k & 1);
            bool valid = ((unsigned)yy < HIMG) && ((unsigned)xx < WIMG);
            float wk = ((k >> 1) ? fy : 1.f - fy) * ((k & 1) ? fx : 1.f - fx);
            wk = valid ? wk * mk : 0.f;
            int yc = min(max(yy, 0), HIMG - 1);
            int xc = min(max(xx, 0), WIMG - 1);
            sidx[k][n][pp] = (unsigned short)(yc * WIMG + xc);
            swgt[k][n][pp] = wk;
        }
    }
    __syncthreads();

    int pp = tid & 63;
    int cq = __builtin_amdgcn_readfirstlane(tid >> 6);    // channel-quad 0..3
    int obase = __builtin_amdgcn_readfirstlane((tid >> 6) * 32);
    float acc[32];
#pragma unroll
    for (int i = 0; i < 32; ++i) acc[i] = 0.f;
    const float4* yb4 = (const float4*)(y1t + (size_t)b * HWSZ * 128);

    for (int cc = 0; cc < 128; cc += 16) {
        // Stage 2a: build val tile [k=16c*9n][64p]; this thread: pixel pp, channels cc+cq*4 .. +3
        int cofs = (cc >> 2) + cq;    // float4 offset within 32-float4 pixel row
#pragma unroll
        for (int n = 0; n < 9; ++n) {
            float4 v = { 0.f, 0.f, 0.f, 0.f };
#pragma unroll
            for (int k = 0; k < 4; ++k) {
                float wk = swgt[k][n][pp];
                int id = sidx[k][n][pp];
                float4 t = yb4[(size_t)id * 32 + cofs];
                v.x = fmaf(wk, t.x, v.x);
                v.y = fmaf(wk, t.y, v.y);
                v.z = fmaf(wk, t.z, v.z);
                v.w = fmaf(wk, t.w, v.w);
            }
            int kb = cq * 4 * 9 + n;
            sval[kb     ][pp] = v.x;
            sval[kb + 9 ][pp] = v.y;
            sval[kb + 18][pp] = v.z;
            sval[kb + 27][pp] = v.w;
        }
        __syncthreads();
        // Stage 2b: FMA against wave-uniform scalar weights
        const float* wbase = w + (size_t)obase * 1152 + (size_t)cc * 9;
#pragma unroll 4
        for (int k = 0; k < 144; ++k) {
            float xv = sval[k][pp];
#pragma unroll
            for (int i = 0; i < 32; ++i)
                acc[i] = fmaf(xv, wbase[(size_t)i * 1152 + k], acc[i]);
        }
        __syncthreads();
    }

    float* zb = z + (size_t)b * 128 * HWSZ + p0 + pp;
#pragma unroll
    for (int i = 0; i < 32; ++i) {
        int o = obase + i;
        float inv = g[o] * rsqrtf(vv[o] + BEPS);
        float bet = bb[o] - mm[o] * inv;
        zb[(size_t)o * HWSZ] = bn_silu(acc[i] + bias[o], inv, bet);
    }
}

// ---------------- Kernel D: cv2 (1x1, 128->256) + bn3 + silu + residual ----------------
__global__ __launch_bounds__(256) void k_cv2(
    const float* __restrict__ z, const float* __restrict__ x,
    const float* __restrict__ w,
    const float* __restrict__ g, const float* __restrict__ bb,
    const float* __restrict__ mm, const float* __restrict__ vv,
    float* __restrict__ out)
{
    __shared__ float zt[128][64];
    int blk = blockIdx.x;
    int b = blk / 200;
    int r = blk % 200;
    int pt = r >> 1, oh = r & 1;
    int p0 = pt * 64;
    int tid = threadIdx.x;
    for (int i = tid; i < 128 * 64; i += 256) {
        int c = i >> 6, pp = i & 63;
        zt[c][pp] = z[((size_t)b * 128 + c) * HWSZ + p0 + pp];
    }
    __syncthreads();
    int p = tid & 63;
    int obase = __builtin_amdgcn_readfirstlane((tid >> 6) * 32 + oh * 128);
    float acc[32];
#pragma unroll
    for (int i = 0; i < 32; ++i) acc[i] = 0.f;
#pragma unroll 4
    for (int c = 0; c < 128; ++c) {
        float zv = zt[c][p];
        const float* wrow = w + (size_t)obase * 128 + c;
#pragma unroll
        for (int i = 0; i < 32; ++i)
            acc[i] = fmaf(zv, wrow[(size_t)i * 128], acc[i]);
    }
    const float* xb = x + (size_t)b * 256 * HWSZ + p0 + p;
    float* ob = out + (size_t)b * 256 * HWSZ + p0 + p;
#pragma unroll
    for (int i = 0; i < 32; ++i) {
        int o = obase + i;
        float inv = g[o] * rsqrtf(vv[o] + BEPS);
        float bet = bb[o] - mm[o] * inv;
        ob[(size_t)o * HWSZ] = xb[(size_t)o * HWSZ] + bn_silu(acc[i], inv, bet);
    }
}

extern "C" void kernel_launch(void* const* d_in, const int* in_sizes, int n_in,
                              void* d_out, int out_size, void* d_ws, size_t ws_size,
                              hipStream_t stream) {
    const float* x     = (const float*)d_in[0];
    const float* cv1w  = (const float*)d_in[1];
    const float* bn1g  = (const float*)d_in[2];
    const float* bn1b  = (const float*)d_in[3];
    const float* bn1m  = (const float*)d_in[4];
    const float* bn1v  = (const float*)d_in[5];
    const float* offw  = (const float*)d_in[6];
    const float* offb  = (const float*)d_in[7];
    const float* dcnw  = (const float*)d_in[8];
    const float* dcnb  = (const float*)d_in[9];
    const float* bn2g  = (const float*)d_in[10];
    const float* bn2b  = (const float*)d_in[11];
    const float* bn2m  = (const float*)d_in[12];
    const float* bn2v  = (const float*)d_in[13];
    const float* cv2w  = (const float*)d_in[14];
    const float* bn3g  = (const float*)d_in[15];
    const float* bn3b  = (const float*)d_in[16];
    const float* bn3m  = (const float*)d_in[17];
    const float* bn3v  = (const float*)d_in[18];
    float* out = (float*)d_out;

    float* y1  = (float*)d_ws;                        // 8*128*6400 chan-major
    float* y1t = y1  + (size_t)8 * 128 * HWSZ;        // 8*6400*128 pixel-major
    float* raw = y1t + (size_t)8 * 128 * HWSZ;        // 8*27*6400
    float* z   = raw + (size_t)8 * 27 * HWSZ;         // 8*128*6400

    k_cv1<<<800, 256, 0, stream>>>(x, cv1w, bn1g, bn1b, bn1m, bn1v, y1, y1t);
    k_off<<<200, 256, 0, stream>>>(y1, offw, offb, raw);
    k_dcn<<<800, 256, 0, stream>>>(y1t, raw, dcnw, dcnb, bn2g, bn2b, bn2m, bn2v, z);
    k_cv2<<<1600, 256, 0, stream>>>(z, x, cv2w, bn3g, bn3b, bn3m, bn3v, out);
}

// Round 3
// 234.336 us; speedup vs baseline: 6.4432x; 6.4432x over previous
//
#include <hip/hip_runtime.h>
#include <math.h>

#define HWSZ 6400
#define WIMG 80
#define HIMG 80
#define BEPS 1e-5f

typedef __attribute__((ext_vector_type(8))) short short8;
typedef __attribute__((ext_vector_type(4))) float f32x4;

__device__ __forceinline__ unsigned short f2b(float f) {
    unsigned u = __builtin_bit_cast(unsigned, f);
    u += 0x7fffu + ((u >> 16) & 1u);
    return (unsigned short)(u >> 16);
}
__device__ __forceinline__ float b2f(unsigned short h) {
    unsigned u = ((unsigned)h) << 16;
    return __builtin_bit_cast(float, u);
}
__device__ __forceinline__ float silu_f(float t) { return t / (1.f + __expf(-t)); }

// B-fragment LDS layout: [kstep(sub)][ntile][n16][q-octet][8] with one pad octet
// per pixel (40 elements per (sub,nt,n16) row) to spread write banks.
#define BPOS(sub, nt, n16, q) (((((sub)*4 + (nt))*16 + (n16))*40) + (q)*8)

// ---------------- prep: BN-fold + bf16 A-fragment prepack -------------------
// apk*: [mt][ks][lane][8] bf16, element = w'[o = mt*16+(lane&15)][k = ks*32+(lane>>4)*8+j]
// conv kernels use k' = tap*128 + c ordering.
__global__ __launch_bounds__(256) void k_prep(
    const float* __restrict__ cv1w, const float* __restrict__ g1, const float* __restrict__ b1,
    const float* __restrict__ m1, const float* __restrict__ v1,
    const float* __restrict__ offw, const float* __restrict__ offb,
    const float* __restrict__ dcnw, const float* __restrict__ dcnb,
    const float* __restrict__ g2, const float* __restrict__ b2,
    const float* __restrict__ m2, const float* __restrict__ v2,
    const float* __restrict__ cv2w, const float* __restrict__ g3, const float* __restrict__ b3,
    const float* __restrict__ m3, const float* __restrict__ v3,
    unsigned short* __restrict__ apk1, unsigned short* __restrict__ apko,
    unsigned short* __restrict__ apkd, unsigned short* __restrict__ apk2,
    float* __restrict__ bias1, float* __restrict__ biaso,
    float* __restrict__ bias2, float* __restrict__ bias3)
{
    int idx = blockIdx.x * 256 + threadIdx.x;
    if (idx < 32768) {                       // cv1: [8 mt][8 ks][64][8], K = 256 ch
        int j = idx & 7, L = (idx >> 3) & 63, ks = (idx >> 9) & 7, mt = idx >> 12;
        int o = mt * 16 + (L & 15), k = ks * 32 + (L >> 4) * 8 + j;
        float inv = g1[o] * rsqrtf(v1[o] + BEPS);
        apk1[idx] = f2b(cv1w[o * 256 + k] * inv);
    } else if (idx < 69632) {                // off: [2 mt][36 ks][64][8], k' = n*128+c, rows>=27 zero
        int t = idx - 32768;
        int j = t & 7, L = (t >> 3) & 63;
        int mt = t / 18432, rem = t % 18432, ks = rem >> 9;
        int o = mt * 16 + (L & 15);
        int kp = ks * 32 + (L >> 4) * 8 + j;
        int n = kp >> 7, c = kp & 127;
        float wv = (o < 27) ? offw[(size_t)(o * 128 + c) * 9 + n] : 0.f;
        apko[t] = f2b(wv);
    } else if (idx < 217088) {               // dcn: [8 mt][36 ks][64][8], k' = n*128+c, BN2 fold
        int t = idx - 69632;
        int j = t & 7, L = (t >> 3) & 63;
        int mt = t / 18432, rem = t % 18432, ks = rem >> 9;
        int o = mt * 16 + (L & 15);
        int kp = ks * 32 + (L >> 4) * 8 + j;
        int n = kp >> 7, c = kp & 127;
        float inv = g2[o] * rsqrtf(v2[o] + BEPS);
        apkd[t] = f2b(dcnw[(size_t)(o * 128 + c) * 9 + n] * inv);
    } else if (idx < 249856) {               // cv2: [16 mt][4 ks][64][8], BN3 fold
        int t = idx - 217088;
        int j = t & 7, L = (t >> 3) & 63, ks = (t >> 9) & 3, mt = t >> 11;
        int o = mt * 16 + (L & 15), k = ks * 32 + (L >> 4) * 8 + j;
        float inv = g3[o] * rsqrtf(v3[o] + BEPS);
        apk2[t] = f2b(cv2w[o * 128 + k] * inv);
    } else if (idx < 250395) {               // biases
        int t = idx - 249856;
        if (t < 128) { float inv = g1[t] * rsqrtf(v1[t] + BEPS); bias1[t] = b1[t] - m1[t] * inv; }
        else if (t < 155) { biaso[t - 128] = offb[t - 128]; }
        else if (t < 283) { int o = t - 155; float inv = g2[o] * rsqrtf(v2[o] + BEPS);
                            bias2[o] = dcnb[o] * inv + b2[o] - m2[o] * inv; }
        else { int o = t - 283; float inv = g3[o] * rsqrtf(v3[o] + BEPS); bias3[o] = b3[o] - m3[o] * inv; }
    }
}

// ---------------- cv1: 1x1 (256->128) + bn1 + silu -> y1t (pixel-major bf16) ----
// grid 800, 256 thr. Block tile O=128, P=64. MFMA 16x16x32 bf16.
__global__ __launch_bounds__(256) void k_cv1(
    const float* __restrict__ x, const unsigned short* __restrict__ apk1,
    const float* __restrict__ bias1, unsigned short* __restrict__ y1t)
{
    __shared__ __align__(16) unsigned short sB[20480];   // 8 ks * 4 nt * 16 * 40
    int blk = blockIdx.x;
    int b = blk / 100, pt = blk % 100;
    int p0 = pt * 64;
    int tid = threadIdx.x;
    int lane = tid & 63;
    int w = tid >> 6;
    // stage: x chan-major fp32 -> bf16 B-frags (lanes = pixels, coalesced 256B loads)
    {
        int px = lane, q = w;
        const float* xb = x + (size_t)b * 256 * HWSZ + p0 + px;
        for (int ks = 0; ks < 8; ++ks) {
            short8 v;
#pragma unroll
            for (int j = 0; j < 8; ++j)
                v[j] = (short)f2b(xb[(size_t)(ks * 32 + q * 8 + j) * HWSZ]);
            *(short8*)&sB[((ks * 4 + (px >> 4)) * 16 + (px & 15)) * 40 + q * 8] = v;
        }
    }
    __syncthreads();
    int n16 = lane & 15, qd = lane >> 4;
    f32x4 acc[2][4];
#pragma unroll
    for (int mi = 0; mi < 2; ++mi)
#pragma unroll
        for (int nt = 0; nt < 4; ++nt) acc[mi][nt] = (f32x4){0.f, 0.f, 0.f, 0.f};
    for (int ks = 0; ks < 8; ++ks) {
        short8 bf[4];
#pragma unroll
        for (int nt = 0; nt < 4; ++nt)
            bf[nt] = *(const short8*)&sB[((ks * 4 + nt) * 16 + n16) * 40 + qd * 8];
#pragma unroll
        for (int mi = 0; mi < 2; ++mi) {
            int mt = w * 2 + mi;
            short8 af = *(const short8*)&apk1[(size_t)((mt * 8 + ks) * 64 + lane) * 8];
#pragma unroll
            for (int nt = 0; nt < 4; ++nt)
                acc[mi][nt] = __builtin_amdgcn_mfma_f32_16x16x32_bf16(af, bf[nt], acc[mi][nt], 0, 0, 0);
        }
    }
    __syncthreads();
    // epilogue: silu, transpose to pixel-major bf16 via LDS, coalesced store
#pragma unroll
    for (int mi = 0; mi < 2; ++mi)
#pragma unroll
        for (int nt = 0; nt < 4; ++nt)
#pragma unroll
            for (int r = 0; r < 4; ++r) {
                int o = w * 32 + mi * 16 + qd * 4 + r;
                float sv = silu_f(acc[mi][nt][r] + bias1[o]);
                sB[(nt * 16 + n16) * 136 + o] = f2b(sv);
            }
    __syncthreads();
    {
        int px = tid >> 2, qq = tid & 3;
        unsigned short* ytb = y1t + ((size_t)b * HWSZ + p0 + px) * 128;
#pragma unroll
        for (int seg = 0; seg < 4; ++seg) {
            short8 v = *(const short8*)&sB[px * 136 + qq * 32 + seg * 8];
            *(short8*)&ytb[qq * 32 + seg * 8] = v;
        }
    }
}

// ---------------- off: 3x3 conv (128->27) + bias, sigmoid on mask ------------
// grid 800, 256 thr. M=32 (pad), K=1152 (tap-major), P=64. raw stays fp32 chan-major.
__global__ __launch_bounds__(256) void k_off(
    const unsigned short* __restrict__ y1t, const unsigned short* __restrict__ apko,
    const float* __restrict__ biaso, float* __restrict__ raw)
{
    __shared__ __align__(16) unsigned short sV[10240];   // 4 sub * 4 nt * 16 * 40
    int blk = blockIdx.x;
    int b = blk / 100, pt = blk % 100;
    int p0 = pt * 64;
    int tid = threadIdx.x;
    int lane = tid & 63, w = tid >> 6;
    int n16 = lane & 15, qd = lane >> 4;
    int pxl = tid >> 2, q = tid & 3;
    int p = p0 + pxl;
    int h = p / WIMG, wx = p % WIMG;
    const unsigned short* yb = y1t + (size_t)b * HWSZ * 128;
    f32x4 acc[2];
    acc[0] = (f32x4){0.f, 0.f, 0.f, 0.f};
    acc[1] = (f32x4){0.f, 0.f, 0.f, 0.f};
    const short8 zz = {0, 0, 0, 0, 0, 0, 0, 0};
    for (int n = 0; n < 9; ++n) {
        int hh = h - 1 + n / 3, ww = wx - 1 + n % 3;
        bool valid = ((unsigned)hh < HIMG) && ((unsigned)ww < WIMG);
        int spx = valid ? hh * WIMG + ww : 0;
        const unsigned short* ys = yb + (size_t)spx * 128 + q * 8;
#pragma unroll
        for (int sub = 0; sub < 4; ++sub) {
            short8 v = *(const short8*)&ys[sub * 32];
            if (!valid) v = zz;
            *(short8*)&sV[BPOS(sub, pxl >> 4, pxl & 15, q)] = v;
        }
        __syncthreads();
#pragma unroll
        for (int sub = 0; sub < 4; ++sub) {
            int ks = n * 4 + sub;
            short8 bf = *(const short8*)&sV[BPOS(sub, w, n16, qd)];
#pragma unroll
            for (int mi = 0; mi < 2; ++mi) {
                short8 af = *(const short8*)&apko[(size_t)((mi * 36 + ks) * 64 + lane) * 8];
                acc[mi] = __builtin_amdgcn_mfma_f32_16x16x32_bf16(af, bf, acc[mi], 0, 0, 0);
            }
        }
        __syncthreads();
    }
    float* rb = raw + (size_t)b * 27 * HWSZ + p0 + w * 16 + n16;
#pragma unroll
    for (int mi = 0; mi < 2; ++mi)
#pragma unroll
        for (int r = 0; r < 4; ++r) {
            int o = mi * 16 + qd * 4 + r;
            if (o < 27) {
                float t = acc[mi][r] + biaso[o];
                if (o >= 18) t = 1.f / (1.f + __expf(-t));
                rb[(size_t)o * HWSZ] = t;
            }
        }
}

// ---------------- dcn: DCNv2 + bn2 + silu -> zt (pixel-major bf16) -----------
// grid 800, 256 thr. O=128, K=1152 tap-major, P=64.
__global__ __launch_bounds__(256) void k_dcn(
    const unsigned short* __restrict__ y1t, const float* __restrict__ raw,
    const unsigned short* __restrict__ apkd, const float* __restrict__ bias2,
    unsigned short* __restrict__ zt)
{
    __shared__ float swgt[4][9][64];
    __shared__ unsigned short sidx[4][9][64];
    __shared__ __align__(16) unsigned short sV[10240];
    int blk = blockIdx.x;
    int b = blk / 100, pt = blk % 100;
    int p0 = pt * 64;
    int tid = threadIdx.x;

    // stage 1: decode offsets -> 4 corner (idx, weight) per (tap, pixel)
    for (int i = tid; i < 576; i += 256) {
        int n = i / 64, pp = i % 64;
        int p = p0 + pp;
        int h = p / WIMG, wx = p % WIMG;
        const float* rb = raw + (size_t)b * 27 * HWSZ + p;
        float dy = rb[(size_t)(2 * n) * HWSZ];
        float dx = rb[(size_t)(2 * n + 1) * HWSZ];
        float mk = rb[(size_t)(18 + n) * HWSZ];
        float py = (float)(h - 1 + n / 3) + dy;
        float px = (float)(wx - 1 + n % 3) + dx;
        float y0f = floorf(py), x0f = floorf(px);
        float fy = py - y0f, fx = px - x0f;
        int y0 = (int)y0f, x0 = (int)x0f;
#pragma unroll
        for (int k = 0; k < 4; ++k) {
            int yy = y0 + (k >> 1);
            int xx = x0 + (k & 1);
            bool valid = ((unsigned)yy < HIMG) && ((unsigned)xx < WIMG);
            float wk = ((k >> 1) ? fy : 1.f - fy) * ((k & 1) ? fx : 1.f - fx);
            wk = valid ? wk * mk : 0.f;
            int yc = min(max(yy, 0), HIMG - 1);
            int xc = min(max(xx, 0), WIMG - 1);
            sidx[k][n][pp] = (unsigned short)(yc * WIMG + xc);
            swgt[k][n][pp] = wk;
        }
    }
    __syncthreads();

    int lane = tid & 63, w = tid >> 6;
    int n16 = lane & 15, qd = lane >> 4;
    int pxl = tid >> 2, q = tid & 3;
    const unsigned short* yb = y1t + (size_t)b * HWSZ * 128;
    f32x4 acc[2][4];
#pragma unroll
    for (int mi = 0; mi < 2; ++mi)
#pragma unroll
        for (int nt = 0; nt < 4; ++nt) acc[mi][nt] = (f32x4){0.f, 0.f, 0.f, 0.f};

    for (int n = 0; n < 9; ++n) {
        // gather + bilinear: this thread = (pixel pxl, ch-octet q), 32 ch across 4 ksteps
        float av[4][8];
#pragma unroll
        for (int sub = 0; sub < 4; ++sub)
#pragma unroll
            for (int j = 0; j < 8; ++j) av[sub][j] = 0.f;
#pragma unroll
        for (int k = 0; k < 4; ++k) {
            float wk = swgt[k][n][pxl];
            const unsigned short* ys = yb + (size_t)sidx[k][n][pxl] * 128 + q * 8;
#pragma unroll
            for (int sub = 0; sub < 4; ++sub) {
                short8 v = *(const short8*)&ys[sub * 32];
#pragma unroll
                for (int j = 0; j < 8; ++j)
                    av[sub][j] = fmaf(wk, b2f((unsigned short)v[j]), av[sub][j]);
            }
        }
#pragma unroll
        for (int sub = 0; sub < 4; ++sub) {
            short8 v;
#pragma unroll
            for (int j = 0; j < 8; ++j) v[j] = (short)f2b(av[sub][j]);
            *(short8*)&sV[BPOS(sub, pxl >> 4, pxl & 15, q)] = v;
        }
        __syncthreads();
#pragma unroll
        for (int sub = 0; sub < 4; ++sub) {
            int ks = n * 4 + sub;
            short8 bf[4];
#pragma unroll
            for (int nt = 0; nt < 4; ++nt)
                bf[nt] = *(const short8*)&sV[BPOS(sub, nt, n16, qd)];
#pragma unroll
            for (int mi = 0; mi < 2; ++mi) {
                short8 af = *(const short8*)&apkd[(size_t)(((2 * w + mi) * 36 + ks) * 64 + lane) * 8];
#pragma unroll
                for (int nt = 0; nt < 4; ++nt)
                    acc[mi][nt] = __builtin_amdgcn_mfma_f32_16x16x32_bf16(af, bf[nt], acc[mi][nt], 0, 0, 0);
            }
        }
        __syncthreads();
    }
    // epilogue: bn2(fused)+silu, transpose to pixel-major bf16 via LDS (reuse sV)
#pragma unroll
    for (int mi = 0; mi < 2; ++mi)
#pragma unroll
        for (int nt = 0; nt < 4; ++nt)
#pragma unroll
            for (int r = 0; r < 4; ++r) {
                int o = w * 32 + mi * 16 + qd * 4 + r;
                float sv = silu_f(acc[mi][nt][r] + bias2[o]);
                sV[(nt * 16 + n16) * 136 + o] = f2b(sv);
            }
    __syncthreads();
    {
        int px = tid >> 2, qq = tid & 3;
        unsigned short* zb = zt + ((size_t)b * HWSZ + p0 + px) * 128;
#pragma unroll
        for (int seg = 0; seg < 4; ++seg) {
            short8 v = *(const short8*)&sV[px * 136 + qq * 32 + seg * 8];
            *(short8*)&zb[qq * 32 + seg * 8] = v;
        }
    }
}

// ---------------- cv2: 1x1 (128->256) + bn3 + silu + residual ----------------
// grid 800, 256 thr. O=256, K=128, P=64. B-frags straight from global zt (no LDS).
__global__ __launch_bounds__(256) void k_cv2(
    const unsigned short* __restrict__ zt, const float* __restrict__ x,
    const unsigned short* __restrict__ apk2, const float* __restrict__ bias3,
    float* __restrict__ out)
{
    int blk = blockIdx.x;
    int b = blk / 100, pt = blk % 100;
    int p0 = pt * 64;
    int tid = threadIdx.x;
    int lane = tid & 63, w = tid >> 6;
    int n16 = lane & 15, qd = lane >> 4;
    const unsigned short* zb = zt + ((size_t)b * HWSZ + p0) * 128;
    f32x4 acc[4][4];
#pragma unroll
    for (int mi = 0; mi < 4; ++mi)
#pragma unroll
        for (int nt = 0; nt < 4; ++nt) acc[mi][nt] = (f32x4){0.f, 0.f, 0.f, 0.f};
#pragma unroll
    for (int ks = 0; ks < 4; ++ks) {
        short8 bf[4];
#pragma unroll
        for (int nt = 0; nt < 4; ++nt)
            bf[nt] = *(const short8*)&zb[(size_t)(nt * 16 + n16) * 128 + ks * 32 + qd * 8];
#pragma unroll
        for (int mi = 0; mi < 4; ++mi) {
            int mt = w * 4 + mi;
            short8 af = *(const short8*)&apk2[(size_t)((mt * 4 + ks) * 64 + lane) * 8];
#pragma unroll
            for (int nt = 0; nt < 4; ++nt)
                acc[mi][nt] = __builtin_amdgcn_mfma_f32_16x16x32_bf16(af, bf[nt], acc[mi][nt], 0, 0, 0);
        }
    }
    const float* xb = x + (size_t)b * 256 * HWSZ;
    float* ob = out + (size_t)b * 256 * HWSZ;
#pragma unroll
    for (int mi = 0; mi < 4; ++mi)
#pragma unroll
        for (int nt = 0; nt < 4; ++nt)
#pragma unroll
            for (int r = 0; r < 4; ++r) {
                int o = w * 64 + mi * 16 + qd * 4 + r;
                size_t idx = (size_t)o * HWSZ + p0 + nt * 16 + n16;
                ob[idx] = xb[idx] + silu_f(acc[mi][nt][r] + bias3[o]);
            }
}

extern "C" void kernel_launch(void* const* d_in, const int* in_sizes, int n_in,
                              void* d_out, int out_size, void* d_ws, size_t ws_size,
                              hipStream_t stream) {
    const float* x     = (const float*)d_in[0];
    const float* cv1w  = (const float*)d_in[1];
    const float* bn1g  = (const float*)d_in[2];
    const float* bn1b  = (const float*)d_in[3];
    const float* bn1m  = (const float*)d_in[4];
    const float* bn1v  = (const float*)d_in[5];
    const float* offw  = (const float*)d_in[6];
    const float* offb  = (const float*)d_in[7];
    const float* dcnw  = (const float*)d_in[8];
    const float* dcnb  = (const float*)d_in[9];
    const float* bn2g  = (const float*)d_in[10];
    const float* bn2b  = (const float*)d_in[11];
    const float* bn2m  = (const float*)d_in[12];
    const float* bn2v  = (const float*)d_in[13];
    const float* cv2w  = (const float*)d_in[14];
    const float* bn3g  = (const float*)d_in[15];
    const float* bn3b  = (const float*)d_in[16];
    const float* bn3m  = (const float*)d_in[17];
    const float* bn3v  = (const float*)d_in[18];
    float* out = (float*)d_out;

    // workspace layout (float units)
    float* base = (float*)d_ws;
    unsigned short* y1t = (unsigned short*)base;                 // 8*6400*128 bf16 = 3,276,800 f
    float* raw   = base + 3276800;                               // 8*27*6400   = 1,382,400 f
    unsigned short* zt  = (unsigned short*)(base + 4659200);     // 8*6400*128 bf16 = 3,276,800 f
    unsigned short* apk1 = (unsigned short*)(base + 7936000);    // 32768  ush = 16384 f
    unsigned short* apko = (unsigned short*)(base + 7952384);    // 36864  ush = 18432 f
    unsigned short* apkd = (unsigned short*)(base + 7970816);    // 147456 ush = 73728 f
    unsigned short* apk2 = (unsigned short*)(base + 8044544);    // 32768  ush = 16384 f
    float* bias1 = base + 8060928;                               // 128
    float* biaso = base + 8061056;                               // 27 (pad 32)
    float* bias2 = base + 8061088;                               // 128
    float* bias3 = base + 8061216;                               // 256

    k_prep<<<979, 256, 0, stream>>>(cv1w, bn1g, bn1b, bn1m, bn1v,
                                    offw, offb, dcnw, dcnb,
                                    bn2g, bn2b, bn2m, bn2v,
                                    cv2w, bn3g, bn3b, bn3m, bn3v,
                                    apk1, apko, apkd, apk2,
                                    bias1, biaso, bias2, bias3);
    k_cv1<<<800, 256, 0, stream>>>(x, apk1, bias1, y1t);
    k_off<<<800, 256, 0, stream>>>(y1t, apko, biaso, raw);
    k_dcn<<<800, 256, 0, stream>>>(y1t, raw, apkd, bias2, zt);
    k_cv2<<<800, 256, 0, stream>>>(zt, x, apk2, bias3, out);
}